// Round 11
// baseline (415.596 us; speedup 1.0000x reference)
//
#include <hip/hip_runtime.h>
#include <hip/hip_fp8.h>
#include <stdint.h>

#define TT 500
#define HT 250
#define NB 32
#define RS 1024
#define CD 5120
#define LT 400
#define NC 396
#define NEGF (-1e30f)
#define L2E 1.4426950408889634f
#define LN2f 0.6931471805599453f

// transposed fp8 image: slab s=t*32+b, 5120 B: col c (0..4) at c*1024 + state
#define SLAB_T 5120
#define IMGT_BYTES (500ull*32*5120)          // 81,920,000
// ctc stream image: 800 floats/slab: [gi]=stay(gi<396), [400+gi]=movein, pads=0
#define IMGS_BYTES (500ull*32*800*4)         // 51,200,000

#define WS_AT 0
#define WS_BT (NB*RS)
#define WS_AC (2*NB*RS)
#define WS_BC (2*NB*RS + NB*NC)
#define WSF_FLOATS (2*NB*RS + 2*NB*NC)

#define SMEM_FAST (8*SLAB_T + 2*RS*4)        // 49152
#define SMEM_FB   (5*20480 + 2*RS*4)         // 110592 (fp32 fallback)

#define SYNC_FAST() do{ __builtin_amdgcn_sched_barrier(0); \
    asm volatile("s_waitcnt vmcnt(4) lgkmcnt(0)"); \
    __builtin_amdgcn_s_barrier(); __builtin_amdgcn_sched_barrier(0);}while(0)
#define SYNC_FB() do{ __builtin_amdgcn_sched_barrier(0); \
    asm volatile("s_waitcnt vmcnt(10) lgkmcnt(0)"); \
    __builtin_amdgcn_s_barrier(); __builtin_amdgcn_sched_barrier(0);}while(0)
#define ROT5(x) do { x = (x == 4) ? 0 : x + 1; } while (0)

__device__ __forceinline__ float f8d(unsigned v){
    __hip_fp8_e4m3 t; t.__x = (__hip_fp8_storage_t)(v & 0xffu); return (float)t;
}
__device__ __forceinline__ float lse5(float t0,float t1,float t2,float t3,float t4){
    float mx = fmaxf(fmaxf(fmaxf(t0,t1),t2), fmaxf(t3,t4));
    float e = exp2f(t0-mx)+exp2f(t1-mx)+exp2f(t2-mx)+exp2f(t3-mx)+exp2f(t4-mx);
    return mx + log2f(e);
}
__device__ __forceinline__ int bsw(int s){ return s ^ (((s>>6)&7)<<2); }

// ===================== fast trellis staging (transposed fp8) ================
__device__ __forceinline__ void stage_t(const unsigned char* imgT, int t, int b,
                                        char* sm, int slot, int w, int lane){
    const unsigned char* src = imgT + ((size_t)t*NB + b)*SLAB_T + w*1280;
    char* dst = sm + slot*SLAB_T + w*1280;
    __builtin_amdgcn_global_load_lds((const __attribute__((address_space(1))) void*)(src + lane*16),
        (__attribute__((address_space(3))) void*)dst, 16,0,0);
    __builtin_amdgcn_global_load_lds((const __attribute__((address_space(1))) void*)(src + 1024 + lane*4),
        (__attribute__((address_space(3))) void*)(dst+1024), 4,0,0);
}

// ===================== fast trellis fwd: 2-step fused, 125 phases ===========
__device__ void trellis2_fwd(const unsigned char* imgT, float* wsf, int b,
                             int tid, char* sm){
    const int w = tid>>6, lane = tid&63;
    float* A0 = (float*)(sm + 8*SLAB_T);
    float* A1 = A0 + RS;
    *(float4*)&A0[4*tid] = make_float4(0.f,0.f,0.f,0.f);
#pragma unroll
    for (int p = 0; p < 6; ++p) stage_t(imgT, p, b, sm, p, w, lane);
    __syncthreads();

    float ao[4] = {0.f,0.f,0.f,0.f};
    for (int ph = 0; ph < 125; ++ph){
        if (ph) SYNC_FAST();
        int t6 = 2*ph+6; if (t6 > HT-1) t6 = HT-1;
        int t7 = 2*ph+7; if (t7 > HT-1) t7 = HT-1;
        stage_t(imgT, t6, b, sm, t6&7, w, lane);
        stage_t(imgT, t7, b, sm, t7&7, w, lane);
        const char* s0 = sm + ((2*ph)&7)*SLAB_T;
        const char* s1 = sm + ((2*ph+1)&7)*SLAB_T;
        const float* Ar = (ph&1) ? A1 : A0;
        float*       Aw = (ph&1) ? A0 : A1;

        unsigned c0[5], c1[5];
#pragma unroll
        for (int c = 0; c < 5; ++c){
            c0[c] = *(const unsigned*)(s0 + c*1024 + 4*tid);
            c1[c] = *(const unsigned*)(s1 + c*1024 + 4*tid);
        }
        float pr[4][5];
#pragma unroll
        for (int k = 0; k < 4; ++k)
#pragma unroll
            for (int c = 0; c < 5; ++c)
                pr[k][c] = f8d(*(const unsigned char*)(s0 + c*1024 + tid + 256*k));
        float pav[4];
#pragma unroll
        for (int k = 0; k < 4; ++k) pav[k] = Ar[tid + 256*k];
        float ga[4][4];
#pragma unroll
        for (int k = 0; k < 4; ++k)
#pragma unroll
            for (int m = 0; m < 4; ++m)
                ga[k][m] = Ar[(tid>>2) + 64*k + 256*m];

        float a1o[4], a1p[4];
#pragma unroll
        for (int k = 0; k < 4; ++k){
            a1o[k] = lse5(fmaf(f8d(c0[0]>>(8*k)),L2E,ao[k]),
                          fmaf(f8d(c0[1]>>(8*k)),L2E,pav[0]),
                          fmaf(f8d(c0[2]>>(8*k)),L2E,pav[1]),
                          fmaf(f8d(c0[3]>>(8*k)),L2E,pav[2]),
                          fmaf(f8d(c0[4]>>(8*k)),L2E,pav[3]));
            a1p[k] = lse5(fmaf(pr[k][0],L2E,pav[k]),
                          fmaf(pr[k][1],L2E,ga[k][0]),
                          fmaf(pr[k][2],L2E,ga[k][1]),
                          fmaf(pr[k][3],L2E,ga[k][2]),
                          fmaf(pr[k][4],L2E,ga[k][3]));
        }
#pragma unroll
        for (int k = 0; k < 4; ++k)
            ao[k] = lse5(fmaf(f8d(c1[0]>>(8*k)),L2E,a1o[k]),
                         fmaf(f8d(c1[1]>>(8*k)),L2E,a1p[0]),
                         fmaf(f8d(c1[2]>>(8*k)),L2E,a1p[1]),
                         fmaf(f8d(c1[3]>>(8*k)),L2E,a1p[2]),
                         fmaf(f8d(c1[4]>>(8*k)),L2E,a1p[3]));
        *(float4*)&Aw[4*tid] = make_float4(ao[0],ao[1],ao[2],ao[3]);
    }
    *(float4*)&wsf[WS_AT + b*RS + 4*tid] = make_float4(ao[0],ao[1],ao[2],ao[3]);
}

// ===================== fast trellis bwd: 2-step fused =======================
__device__ void trellis2_bwd(const unsigned char* imgT, float* wsf, int b,
                             int tid, char* sm){
    const int w = tid>>6, lane = tid&63;
    float* B0 = (float*)(sm + 8*SLAB_T);
    float* B1 = B0 + RS;
    *(float4*)&B0[4*tid] = make_float4(0.f,0.f,0.f,0.f);
    const int col = tid>>6;                 // wave-uniform
#pragma unroll
    for (int p = 0; p < 6; ++p) stage_t(imgT, TT-1-p, b, sm, (TT-1-p)&7, w, lane);
    __syncthreads();

    float bo[4] = {0.f,0.f,0.f,0.f};
    for (int ph = 0; ph < 125; ++ph){
        if (ph) SYNC_FAST();
        int sA = TT-1-(2*ph+6); if (sA < HT) sA = HT;
        int sB = TT-1-(2*ph+7); if (sB < HT) sB = HT;
        stage_t(imgT, sA, b, sm, sA&7, w, lane);
        stage_t(imgT, sB, b, sm, sB&7, w, lane);
        const char* s1 = sm + ((TT-1-2*ph)&7)*SLAB_T;   // slab t+1
        const char* s0 = sm + ((TT-2-2*ph)&7)*SLAB_T;   // slab t
        const float* Br = (ph&1) ? B1 : B0;
        float*       Bw = (ph&1) ? B0 : B1;

        unsigned ct1[5], ct0_[4], gw[4];
        float st1[4], st0[4];
#pragma unroll
        for (int c = 0; c < 5; ++c) ct1[c] = *(const unsigned*)(s1 + c*1024 + 4*tid);
#pragma unroll
        for (int c = 1; c < 5; ++c) ct0_[c-1] = *(const unsigned*)(s0 + c*1024 + 4*tid);
#pragma unroll
        for (int j = 0; j < 4; ++j){
            st1[j] = f8d(*(const unsigned char*)(s1 + tid + 256*j));
            st0[j] = f8d(*(const unsigned char*)(s0 + tid + 256*j));
        }
#pragma unroll
        for (int k = 0; k < 4; ++k)
            gw[k] = *(const unsigned*)(s1 + (col+1)*1024 + ((16*tid + 4*k) & 1023));

        float4 bc2 = *(const float4*)&Br[(4*tid) ^ (((tid>>4)&7)<<2)];
        float bcv[4] = {bc2.x, bc2.y, bc2.z, bc2.w};
        float4 gc2[4];
#pragma unroll
        for (int k = 0; k < 4; ++k)
            gc2[k] = *(const float4*)&Br[((16*tid + 4*k) & 1023) ^ (((tid>>2)&7)<<2)];

        float b1o[4], b1c[4];
#pragma unroll
        for (int j = 0; j < 4; ++j)
            b1o[j] = lse5(fmaf(st1[j],L2E,bo[j]),
                          fmaf(f8d(ct1[j+1]      ),L2E,bcv[0]),
                          fmaf(f8d(ct1[j+1]>>8   ),L2E,bcv[1]),
                          fmaf(f8d(ct1[j+1]>>16  ),L2E,bcv[2]),
                          fmaf(f8d(ct1[j+1]>>24  ),L2E,bcv[3]));
#pragma unroll
        for (int k = 0; k < 4; ++k)
            b1c[k] = lse5(fmaf(f8d(ct1[0]>>(8*k)),L2E,bcv[k]),
                          fmaf(f8d(gw[k]      ),L2E,gc2[k].x),
                          fmaf(f8d(gw[k]>>8   ),L2E,gc2[k].y),
                          fmaf(f8d(gw[k]>>16  ),L2E,gc2[k].z),
                          fmaf(f8d(gw[k]>>24  ),L2E,gc2[k].w));
#pragma unroll
        for (int j = 0; j < 4; ++j){
            bo[j] = lse5(fmaf(st0[j],L2E,b1o[j]),
                         fmaf(f8d(ct0_[j]      ),L2E,b1c[0]),
                         fmaf(f8d(ct0_[j]>>8   ),L2E,b1c[1]),
                         fmaf(f8d(ct0_[j]>>16  ),L2E,b1c[2]),
                         fmaf(f8d(ct0_[j]>>24  ),L2E,b1c[3]));
            Bw[(tid + 256*j) ^ ((((tid>>6) + 4*j)&7)<<2)] = bo[j];
        }
    }
#pragma unroll
    for (int j = 0; j < 4; ++j)
        wsf[WS_BT + b*RS + tid + 256*j] = bo[j];
}

// ===================== CTC steps (shared) ====================================
__device__ __forceinline__ void cstep(const float (&S)[7], const float (&V)[7],
                                      float (&ac)[7], int lane) {
    float prev = __shfl_up(ac[6], 1, 64);
    float nw[7];
#pragma unroll
    for (int k = 0; k < 7; ++k) {
        float left = k ? ac[k-1] : prev;
        float x = fmaf(S[k], L2E, ac[k]);
        float y = fmaf(V[k], L2E, left);
        if (k == 0) y = (lane == 0) ? NEGF : y;
        float m2 = fmaxf(x, y);
        float d  = fminf(x, y) - m2;
        nw[k] = m2 + log2f(1.0f + exp2f(d));
    }
#pragma unroll
    for (int k = 0; k < 7; ++k) ac[k] = nw[k];
}
__device__ __forceinline__ void cstep_b(const float (&S)[7], const float (&V)[7],
                                        float (&ac)[7], int lane) {
    float nxt = __shfl_down(ac[0], 1, 64);
    float nw[7];
#pragma unroll
    for (int k = 0; k < 7; ++k) {
        int gi = 7*lane + k;
        float bn = (k < 6) ? ac[k+1] : nxt;
        float x = fmaf(S[k], L2E, ac[k]);
        float y = fmaf(V[k], L2E, bn);
        y = (gi < NC-1) ? y : NEGF;
        float m2 = fmaxf(x, y);
        float d  = fminf(x, y) - m2;
        float r  = m2 + log2f(1.0f + exp2f(d));
        nw[k] = (gi < NC) ? r : NEGF;
    }
#pragma unroll
    for (int k = 0; k < 7; ++k) ac[k] = nw[k];
}

// ===================== fast CTC: streaming reads ============================
__device__ void ctcs_run(const float* imgS, const int* tlens, float* wsf,
                         int b, int lane, bool is_fwd){
    const size_t STP = (size_t)NB * 800;
    const float* p = imgS + (size_t)b * 800;
    int si[7], vi[7];
#pragma unroll
    for (int k = 0; k < 7; ++k){
        int gi = 7*lane + k;
        int s_ = gi;              if (s_ > 399) s_ = 399;
        int v_ = is_fwd ? (400 + gi) : (400 + gi + 1);
        if (v_ > 799) v_ = 799;
        si[k] = s_; vi[k] = v_;
    }
    int tl = tlens[b];
    float ac[7];
#pragma unroll
    for (int k = 0; k < 7; ++k){
        int gi = 7*lane + k;
        ac[k] = is_fwd ? ((gi == 0) ? 0.f : NEGF) : ((gi == tl-5) ? 0.f : NEGF);
    }
    float S[5][7], V[5][7];
#pragma unroll
    for (int j = 0; j < 5; ++j){
        size_t t = is_fwd ? (size_t)j : (size_t)(TT-1-j);
#pragma unroll
        for (int k = 0; k < 7; ++k){ S[j][k] = p[t*STP + si[k]]; V[j][k] = p[t*STP + vi[k]]; }
    }
    for (int t = 0; t < HT; t += 5){
#pragma unroll
        for (int j = 0; j < 5; ++j){
            if (is_fwd) cstep(S[j], V[j], ac, lane);
            else        cstep_b(S[j], V[j], ac, lane);
            int ts = t + 5 + j;
            if (ts < HT){
                size_t tt = is_fwd ? (size_t)ts : (size_t)(TT-1-ts);
#pragma unroll
                for (int k = 0; k < 7; ++k){ S[j][k] = p[tt*STP + si[k]]; V[j][k] = p[tt*STP + vi[k]]; }
            }
        }
    }
#pragma unroll
    for (int k = 0; k < 7; ++k){
        int gi = 7*lane + k;
        if (gi < NC) wsf[(is_fwd ? WS_AC : WS_BC) + b*NC + gi] = ac[k];
    }
}

// ===================== fallback: fp32 1-step trellis + gather CTC ===========
__device__ __forceinline__ void compute4f(const float (&f)[20], float (&ao)[4],
                                          float p0, float p1, float p2, float p3){
    ao[0] = lse5(fmaf(f[0],L2E,ao[0]),  fmaf(f[1],L2E,p0),  fmaf(f[2],L2E,p1),
                 fmaf(f[3],L2E,p2),     fmaf(f[4],L2E,p3));
    ao[1] = lse5(fmaf(f[5],L2E,ao[1]),  fmaf(f[6],L2E,p0),  fmaf(f[7],L2E,p1),
                 fmaf(f[8],L2E,p2),     fmaf(f[9],L2E,p3));
    ao[2] = lse5(fmaf(f[10],L2E,ao[2]), fmaf(f[11],L2E,p0), fmaf(f[12],L2E,p1),
                 fmaf(f[13],L2E,p2),    fmaf(f[14],L2E,p3));
    ao[3] = lse5(fmaf(f[15],L2E,ao[3]), fmaf(f[16],L2E,p0), fmaf(f[17],L2E,p1),
                 fmaf(f[18],L2E,p2),    fmaf(f[19],L2E,p3));
}
__device__ __forceinline__ void computeBf(const float (&f)[20], const float (&st)[4],
                                          float (&bo)[4], float4 bc){
    bo[0] = lse5(fmaf(st[0],L2E,bo[0]), fmaf(f[1],L2E,bc.x),  fmaf(f[6],L2E,bc.y),
                 fmaf(f[11],L2E,bc.z),  fmaf(f[16],L2E,bc.w));
    bo[1] = lse5(fmaf(st[1],L2E,bo[1]), fmaf(f[2],L2E,bc.x),  fmaf(f[7],L2E,bc.y),
                 fmaf(f[12],L2E,bc.z),  fmaf(f[17],L2E,bc.w));
    bo[2] = lse5(fmaf(st[2],L2E,bo[2]), fmaf(f[3],L2E,bc.x),  fmaf(f[8],L2E,bc.y),
                 fmaf(f[13],L2E,bc.z),  fmaf(f[18],L2E,bc.w));
    bo[3] = lse5(fmaf(st[3],L2E,bo[3]), fmaf(f[4],L2E,bc.x),  fmaf(f[9],L2E,bc.y),
                 fmaf(f[14],L2E,bc.z),  fmaf(f[19],L2E,bc.w));
}

__device__ void trellis_fb(const float* scores, float* wsf, int c, int tid, char* sm){
    const bool is_fwd = c < NB;
    const int b = c & (NB-1);
    const int w = tid >> 6, lane = tid & 63;
    float* A0 = (float*)(sm + 5*20480);
    float* A1 = A0 + RS;
    *(float4*)&A0[4*tid] = make_float4(0.f,0.f,0.f,0.f);

    auto stage = [&](int t, int slot){
        const char* src = (const char*)(scores + ((size_t)t*NB + b)*(size_t)CD) + w*5120;
        char* dst = sm + slot*20480 + w*5120;
#pragma unroll
        for (int m = 0; m < 5; ++m)
            __builtin_amdgcn_global_load_lds(
                (const __attribute__((address_space(1))) void*)(src + m*1024 + lane*16),
                (__attribute__((address_space(3))) void*)(dst + m*1024), 16, 0, 0);
    };
    auto rd20 = [&](int slot, float (&f)[20]){
        const float4* q4 = (const float4*)(sm + slot*20480 + 80*tid);
        float4 r0=q4[0], r1=q4[1], r2=q4[2], r3=q4[3], r4=q4[4];
        f[0]=r0.x; f[1]=r0.y; f[2]=r0.z; f[3]=r0.w; f[4]=r1.x; f[5]=r1.y; f[6]=r1.z; f[7]=r1.w;
        f[8]=r2.x; f[9]=r2.y; f[10]=r2.z; f[11]=r2.w; f[12]=r3.x; f[13]=r3.y; f[14]=r3.z; f[15]=r3.w;
        f[16]=r4.x; f[17]=r4.y; f[18]=r4.z; f[19]=r4.w;
    };
    auto rdst = [&](int slot, float (&st)[4]){
        const float* slf = (const float*)(sm + slot*20480);
        st[0] = slf[5*tid]; st[1] = slf[5*tid+1280]; st[2] = slf[5*tid+2560]; st[3] = slf[5*tid+3840];
    };

#pragma unroll
    for (int p = 0; p < 4; ++p) stage(is_fwd ? p : (TT-1-p), p);
    __syncthreads();
    float Ma[20], Mb[20], sta[4], stb[4], ao[4] = {0.f,0.f,0.f,0.f};
    rd20(0, Ma);
    if (!is_fwd) rdst(0, sta);
    int s_rd = 1, s_st = 4;
    for (int k = 0; k < HT; k += 2){
        SYNC_FB();
        { int ts = k+4; if (ts > HT-1) ts = HT-1; stage(is_fwd ? ts : (TT-1-ts), s_st); }
        if (is_fwd){
            float p0=A0[tid], p1=A0[tid+256], p2=A0[tid+512], p3=A0[tid+768];
            rd20(s_rd, Mb); compute4f(Ma, ao, p0,p1,p2,p3);
            *(float4*)&A1[4*tid] = make_float4(ao[0],ao[1],ao[2],ao[3]);
        } else {
            float4 bc = *(const float4*)&A0[4*tid];
            rd20(s_rd, Mb); rdst(s_rd, stb); computeBf(Ma, sta, ao, bc);
            A1[tid]=ao[0]; A1[tid+256]=ao[1]; A1[tid+512]=ao[2]; A1[tid+768]=ao[3];
        }
        ROT5(s_rd); ROT5(s_st);
        SYNC_FB();
        { int ts = k+5; if (ts > HT-1) ts = HT-1; stage(is_fwd ? ts : (TT-1-ts), s_st); }
        if (is_fwd){
            float p0=A1[tid], p1=A1[tid+256], p2=A1[tid+512], p3=A1[tid+768];
            rd20(s_rd, Ma); compute4f(Mb, ao, p0,p1,p2,p3);
            *(float4*)&A0[4*tid] = make_float4(ao[0],ao[1],ao[2],ao[3]);
        } else {
            float4 bc = *(const float4*)&A1[4*tid];
            rd20(s_rd, Ma); rdst(s_rd, sta); computeBf(Mb, stb, ao, bc);
            A0[tid]=ao[0]; A0[tid+256]=ao[1]; A0[tid+512]=ao[2]; A0[tid+768]=ao[3];
        }
        ROT5(s_rd); ROT5(s_st);
    }
    if (is_fwd) *(float4*)&wsf[WS_AT + b*RS + 4*tid] = make_float4(ao[0],ao[1],ao[2],ao[3]);
    else {
        wsf[WS_BT+b*RS+tid]=ao[0]; wsf[WS_BT+b*RS+tid+256]=ao[1];
        wsf[WS_BT+b*RS+tid+512]=ao[2]; wsf[WS_BT+b*RS+tid+768]=ao[3];
    }
}

__device__ __forceinline__ int tgv(const int* targets, int b, int i){
    i = i < 0 ? 0 : (i > LT-1 ? LT-1 : i);
    int v = targets[b*LT + i] - 1;
    return v < 0 ? 0 : v;
}
__device__ void ctcg_run(const float* scores, const int* targets, const int* tlens,
                         float* wsf, int b, int lane, bool is_fwd){
    int so[7], mo[7];
#pragma unroll
    for (int k = 0; k < 7; ++k){
        int gi = 7*lane + k;
        if (gi < NC){
            int K = tgv(targets,b,gi);
            K = K*4 + tgv(targets,b,gi+1); K = K*4 + tgv(targets,b,gi+2);
            K = K*4 + tgv(targets,b,gi+3); K = K*4 + tgv(targets,b,gi+4);
            so[k] = K*5;
            if (is_fwd) mo[k] = (gi >= 1) ? (so[k] + tgv(targets,b,gi-1) + 1) : 0;
            else if (gi < NC-1){
                int K2 = tgv(targets,b,gi+1);
                K2 = K2*4 + tgv(targets,b,gi+2); K2 = K2*4 + tgv(targets,b,gi+3);
                K2 = K2*4 + tgv(targets,b,gi+4); K2 = K2*4 + tgv(targets,b,gi+5);
                mo[k] = K2*5 + tgv(targets,b,gi) + 1;
            } else mo[k] = 0;
        } else { so[k] = 0; mo[k] = 0; }
    }
    int tl = tlens[b];
    float ac[7];
#pragma unroll
    for (int k = 0; k < 7; ++k){
        int gi = 7*lane + k;
        ac[k] = is_fwd ? ((gi == 0) ? 0.f : NEGF) : ((gi == tl-5) ? 0.f : NEGF);
    }
    const size_t STP = (size_t)NB*CD;
    const float* qb = scores + (size_t)b*CD;
    float S[5][7], V[5][7];
#pragma unroll
    for (int j = 0; j < 5; ++j){
        const float* q = qb + (size_t)(is_fwd ? j : (TT-1-j))*STP;
#pragma unroll
        for (int k = 0; k < 7; ++k){ S[j][k] = q[so[k]]; V[j][k] = q[mo[k]]; }
    }
    for (int t = 0; t < HT; t += 5){
#pragma unroll
        for (int j = 0; j < 5; ++j){
            if (is_fwd) cstep(S[j],V[j],ac,lane); else cstep_b(S[j],V[j],ac,lane);
            int ts = t + 5 + j;
            if (ts < HT){
                const float* q = qb + (size_t)(is_fwd ? ts : (TT-1-ts))*STP;
#pragma unroll
                for (int k = 0; k < 7; ++k){ S[j][k] = q[so[k]]; V[j][k] = q[mo[k]]; }
            }
        }
    }
#pragma unroll
    for (int k = 0; k < 7; ++k){
        int gi = 7*lane + k;
        if (gi < NC) wsf[(is_fwd ? WS_AC : WS_BC) + b*NC + gi] = ac[k];
    }
}

// ===================== kernel A: convert (transposed fp8 + ctc stream) ======
extern "C" __global__ void __launch_bounds__(256, 1)
conv_all(const float* __restrict__ scores, unsigned char* __restrict__ imgT,
         float* __restrict__ imgS, const int* __restrict__ targets)
{
    const size_t s = blockIdx.x;
    const int tid = threadIdx.x;
    const int b = (int)(s & 31);
    const float* in = scores + s*(size_t)CD;
    const float4* p4 = (const float4*)(in + 20*tid);
    float4 v0 = p4[0], v1 = p4[1], v2 = p4[2], v3 = p4[3], v4 = p4[4];
    float f[20] = {v0.x,v0.y,v0.z,v0.w, v1.x,v1.y,v1.z,v1.w,
                   v2.x,v2.y,v2.z,v2.w, v3.x,v3.y,v3.z,v3.w,
                   v4.x,v4.y,v4.z,v4.w};
    unsigned char* ot = imgT + s*(size_t)SLAB_T;
#pragma unroll
    for (int c = 0; c < 5; ++c){
        unsigned b0,b1,b2,b3;
        { __hip_fp8_e4m3 t(f[c]);    b0 = t.__x; }
        { __hip_fp8_e4m3 t(f[5+c]);  b1 = t.__x; }
        { __hip_fp8_e4m3 t(f[10+c]); b2 = t.__x; }
        { __hip_fp8_e4m3 t(f[15+c]); b3 = t.__x; }
        *(unsigned*)(ot + c*1024 + 4*tid) = b0 | (b1<<8) | (b2<<16) | (b3<<24);
    }
    float* os = imgS + s*(size_t)800;
    for (int i = tid; i < 800; i += 256){
        float v = 0.f;
        if (i < NC){
            int gi = i;
            int K = tgv(targets,b,gi);
            K = K*4 + tgv(targets,b,gi+1); K = K*4 + tgv(targets,b,gi+2);
            K = K*4 + tgv(targets,b,gi+3); K = K*4 + tgv(targets,b,gi+4);
            v = in[K*5];
        } else if (i >= 401 && i <= 400 + NC - 1){
            int gi = i - 400;
            int K = tgv(targets,b,gi);
            K = K*4 + tgv(targets,b,gi+1); K = K*4 + tgv(targets,b,gi+2);
            K = K*4 + tgv(targets,b,gi+3); K = K*4 + tgv(targets,b,gi+4);
            v = in[K*5 + tgv(targets,b,gi-1) + 1];
        }
        os[i] = v;
    }
}

// ===================== kernel B: trellis + ctc ==============================
extern "C" __global__ void __launch_bounds__(256, 1)
main_k(const float* __restrict__ scores, const unsigned char* __restrict__ imgT,
       const float* __restrict__ imgS, const int* __restrict__ targets,
       const int* __restrict__ tlens, float* __restrict__ wsf, int useFast)
{
    extern __shared__ float smf[];
    char* sm = (char*)smf;
    const int tid = threadIdx.x, blk = blockIdx.x;
    if (blk < 2*NB){
        if (useFast){
            if (blk < NB) trellis2_fwd(imgT, wsf, blk, tid, sm);
            else          trellis2_bwd(imgT, wsf, blk-NB, tid, sm);
        } else trellis_fb(scores, wsf, blk, tid, sm);
        return;
    }
    if (tid >= 64) return;
    const int cb = blk - 2*NB;
    const bool is_fwd = cb < NB;
    const int b = cb & (NB-1);
    if (useFast) ctcs_run(imgS, tlens, wsf, b, tid, is_fwd);
    else         ctcg_run(scores, targets, tlens, wsf, b, tid, is_fwd);
}

// ===================== kernel C: combine ====================================
extern "C" __global__ void __launch_bounds__(256, 1)
ctc_crf_combine(const float* __restrict__ wsf, const int* __restrict__ tlens,
                float* __restrict__ out)
{
    const int b = blockIdx.x, tid = threadIdx.x, lane = tid & 63, w = tid >> 6;
    __shared__ float r1[4], r2[4];
    float4 a4 = *(const float4*)&wsf[WS_AT + b*RS + 4*tid];
    float4 b4 = *(const float4*)&wsf[WS_BT + b*RS + 4*tid];
    float v0 = a4.x+b4.x, v1 = a4.y+b4.y, v2 = a4.z+b4.z, v3 = a4.w+b4.w;
    float m = fmaxf(fmaxf(v0,v1), fmaxf(v2,v3));
#pragma unroll
    for (int o = 32; o >= 1; o >>= 1) m = fmaxf(m, __shfl_xor(m, o, 64));
    if (lane == 0) r1[w] = m;
    __syncthreads();
    float g = fmaxf(fmaxf(r1[0],r1[1]), fmaxf(r1[2],r1[3]));
    float e = exp2f(v0-g)+exp2f(v1-g)+exp2f(v2-g)+exp2f(v3-g);
#pragma unroll
    for (int o = 32; o >= 1; o >>= 1) e += __shfl_xor(e, o, 64);
    if (lane == 0) r2[w] = e;
    __syncthreads();
    float zfull = g + log2f(r2[0]+r2[1]+r2[2]+r2[3]);
    __syncthreads();
    float c0 = (tid < NC)     ? wsf[WS_AC + b*NC + tid]       + wsf[WS_BC + b*NC + tid]       : NEGF;
    float c1 = (tid+256 < NC) ? wsf[WS_AC + b*NC + tid + 256] + wsf[WS_BC + b*NC + tid + 256] : NEGF;
    float mc = fmaxf(c0, c1);
#pragma unroll
    for (int o = 32; o >= 1; o >>= 1) mc = fmaxf(mc, __shfl_xor(mc, o, 64));
    if (lane == 0) r1[w] = mc;
    __syncthreads();
    float gc = fmaxf(fmaxf(r1[0],r1[1]), fmaxf(r1[2],r1[3]));
    float ec = exp2f(c0-gc)+exp2f(c1-gc);
#pragma unroll
    for (int o = 32; o >= 1; o >>= 1) ec += __shfl_xor(ec, o, 64);
    if (lane == 0) r2[w] = ec;
    __syncthreads();
    if (tid == 0){
        float zctc = gc + log2f(r2[0]+r2[1]+r2[2]+r2[3]);
        int tl = tlens[b];
        float loss_b = LN2f * (zfull - zctc) / (float)tl;
        atomicAdd(out, loss_b / (float)NB);
    }
}

extern "C" void kernel_launch(void* const* d_in, const int* in_sizes, int n_in,
                              void* d_out, int out_size, void* d_ws, size_t ws_size,
                              hipStream_t stream) {
    const float* scores  = (const float*)d_in[0];
    const int*   targets = (const int*)d_in[1];
    const int*   tlens   = (const int*)d_in[2];
    float* out = (float*)d_out;

    const size_t need = IMGT_BYTES + IMGS_BYTES + (size_t)WSF_FLOATS*4 + 1024;
    const int useFast = (ws_size >= need) ? 1 : 0;
    unsigned char* imgT = (unsigned char*)d_ws;
    float* imgS = (float*)((char*)d_ws + IMGT_BYTES);
    float* wsf  = useFast ? (float*)((char*)d_ws + IMGT_BYTES + IMGS_BYTES)
                          : (float*)d_ws;

    hipFuncSetAttribute((const void*)main_k,
                        hipFuncAttributeMaxDynamicSharedMemorySize, SMEM_FB);
    hipMemsetAsync(out, 0, sizeof(float), stream);
    if (useFast)
        conv_all<<<TT*NB, 256, 0, stream>>>(scores, imgT, imgS, targets);
    main_k<<<4*NB, 256, useFast ? SMEM_FAST : SMEM_FB, stream>>>(
        scores, imgT, imgS, targets, tlens, wsf, useFast);
    ctc_crf_combine<<<NB, 256, 0, stream>>>(wsf, tlens, out);
}

// Round 12
// 295.014 us; speedup vs baseline: 1.4087x; 1.4087x over previous
//
#include <hip/hip_runtime.h>
#include <stdint.h>

#define TT 500
#define HT 250
#define NB 32
#define RS 1024
#define CD 5120
#define LT 400
#define NC 396
#define NEGF (-1e30f)
#define L2E 1.4426950408889634f
#define LN2f 0.6931471805599453f

// ctc stream image: 800 floats/slab: [gi]=stay(gi<396), [400+gi]=movein, pads=0
#define IMGS_BYTES (500ull*32*800*4)         // 51,200,000

#define WS_AT 0
#define WS_BT (NB*RS)
#define WS_AC (2*NB*RS)
#define WS_BC (2*NB*RS + NB*NC)
#define WSF_FLOATS (2*NB*RS + 2*NB*NC)

#define SMEM_TR (5*20480 + 2*RS*4)           // 110592

// renorm: multiply alphas by 2^-24 on steps 7,15,...,247 -> 31 times
#define RENORM_LOG2 744.0f

#define SYNC_TR() do{ __builtin_amdgcn_sched_barrier(0); \
    asm volatile("s_waitcnt vmcnt(10) lgkmcnt(0)"); \
    __builtin_amdgcn_s_barrier(); __builtin_amdgcn_sched_barrier(0);}while(0)
#define ROT5(x) do { x = (x == 4) ? 0 : x + 1; } while (0)

__device__ __forceinline__ float ef(float x){ return exp2f(x * L2E); }  // e^x

// ===================== trellis: fp32 staged, exp-domain compute =============
__device__ void trellis_exp(const float* __restrict__ scores, float* __restrict__ wsf,
                            int c, int tid, char* sm){
    const bool is_fwd = c < NB;
    const int b = c & (NB-1);
    const int w = tid >> 6, lane = tid & 63;
    float* A0 = (float*)(sm + 5*20480);
    float* A1 = A0 + RS;
    *(float4*)&A0[4*tid] = make_float4(1.f,1.f,1.f,1.f);   // exp-domain one

    auto stage = [&](int t, int slot){
        const char* src = (const char*)(scores + ((size_t)t*NB + b)*(size_t)CD) + w*5120;
        char* dst = sm + slot*20480 + w*5120;
#pragma unroll
        for (int m = 0; m < 5; ++m)
            __builtin_amdgcn_global_load_lds(
                (const __attribute__((address_space(1))) void*)(src + m*1024 + lane*16),
                (__attribute__((address_space(3))) void*)(dst + m*1024), 16, 0, 0);
    };
    auto rd20 = [&](int slot, float (&f)[20]){
        const float4* q4 = (const float4*)(sm + slot*20480 + 80*tid);
        float4 r0=q4[0], r1=q4[1], r2=q4[2], r3=q4[3], r4=q4[4];
        f[0]=r0.x; f[1]=r0.y; f[2]=r0.z; f[3]=r0.w; f[4]=r1.x;
        f[5]=r1.y; f[6]=r1.z; f[7]=r1.w; f[8]=r2.x; f[9]=r2.y;
        f[10]=r2.z; f[11]=r2.w; f[12]=r3.x; f[13]=r3.y; f[14]=r3.z;
        f[15]=r3.w; f[16]=r4.x; f[17]=r4.y; f[18]=r4.z; f[19]=r4.w;
    };
    auto rdst = [&](int slot, float (&st)[4]){
        const float* slf = (const float*)(sm + slot*20480);
        st[0] = slf[5*tid]; st[1] = slf[5*tid+1280];
        st[2] = slf[5*tid+2560]; st[3] = slf[5*tid+3840];
    };

#pragma unroll
    for (int p = 0; p < 4; ++p) stage(is_fwd ? p : (TT-1-p), p);
    __syncthreads();

    float Ma[20], Mb[20], sta[4], stb[4];
    float ao[4] = {1.f,1.f,1.f,1.f};
    rd20(0, Ma);
    if (!is_fwd) rdst(0, sta);
    int s_rd = 1, s_st = 4;

    for (int k = 0; k < HT; k += 2){
        // ---- even step k (rs = 1) ----
        SYNC_TR();
        { int ts = k+4; if (ts > HT-1) ts = HT-1; stage(is_fwd ? ts : (TT-1-ts), s_st); }
        if (is_fwd){
            float p0=A0[tid], p1=A0[tid+256], p2=A0[tid+512], p3=A0[tid+768];
            rd20(s_rd, Mb);
#pragma unroll
            for (int s = 0; s < 4; ++s)
                ao[s] = ef(Ma[5*s])*ao[s] + ef(Ma[5*s+1])*p0 + ef(Ma[5*s+2])*p1
                      + ef(Ma[5*s+3])*p2 + ef(Ma[5*s+4])*p3;
            *(float4*)&A1[4*tid] = make_float4(ao[0],ao[1],ao[2],ao[3]);
        } else {
            float4 bc = *(const float4*)&A0[4*tid];
            rd20(s_rd, Mb); rdst(s_rd, stb);
#pragma unroll
            for (int j = 0; j < 4; ++j)
                ao[j] = ef(sta[j])*ao[j] + ef(Ma[1+j])*bc.x + ef(Ma[6+j])*bc.y
                      + ef(Ma[11+j])*bc.z + ef(Ma[16+j])*bc.w;
            A1[tid]=ao[0]; A1[tid+256]=ao[1]; A1[tid+512]=ao[2]; A1[tid+768]=ao[3];
        }
        ROT5(s_rd); ROT5(s_st);

        // ---- odd step k+1 (renorm on steps 7,15,...,247) ----
        SYNC_TR();
        { int ts = k+5; if (ts > HT-1) ts = HT-1; stage(is_fwd ? ts : (TT-1-ts), s_st); }
        {
            const float rs = ((k & 7) == 6) ? 0x1p-24f : 1.0f;
            if (is_fwd){
                float p0=A1[tid], p1=A1[tid+256], p2=A1[tid+512], p3=A1[tid+768];
                rd20(s_rd, Ma);
#pragma unroll
                for (int s = 0; s < 4; ++s)
                    ao[s] = rs*(ef(Mb[5*s])*ao[s] + ef(Mb[5*s+1])*p0 + ef(Mb[5*s+2])*p1
                              + ef(Mb[5*s+3])*p2 + ef(Mb[5*s+4])*p3);
                *(float4*)&A0[4*tid] = make_float4(ao[0],ao[1],ao[2],ao[3]);
            } else {
                float4 bc = *(const float4*)&A1[4*tid];
                rd20(s_rd, Ma); rdst(s_rd, sta);
#pragma unroll
                for (int j = 0; j < 4; ++j)
                    ao[j] = rs*(ef(stb[j])*ao[j] + ef(Mb[1+j])*bc.x + ef(Mb[6+j])*bc.y
                              + ef(Mb[11+j])*bc.z + ef(Mb[16+j])*bc.w);
                A0[tid]=ao[0]; A0[tid+256]=ao[1]; A0[tid+512]=ao[2]; A0[tid+768]=ao[3];
            }
        }
        ROT5(s_rd); ROT5(s_st);
    }

    // epilogue: to log2 domain + renorm offset
    float o0 = log2f(ao[0]) + RENORM_LOG2, o1 = log2f(ao[1]) + RENORM_LOG2;
    float o2 = log2f(ao[2]) + RENORM_LOG2, o3 = log2f(ao[3]) + RENORM_LOG2;
    if (is_fwd){
        *(float4*)&wsf[WS_AT + b*RS + 4*tid] = make_float4(o0,o1,o2,o3);
    } else {
        wsf[WS_BT+b*RS+tid]=o0; wsf[WS_BT+b*RS+tid+256]=o1;
        wsf[WS_BT+b*RS+tid+512]=o2; wsf[WS_BT+b*RS+tid+768]=o3;
    }
}

// ===================== CTC steps (log2 domain) ==============================
__device__ __forceinline__ void cstep(const float (&S)[7], const float (&V)[7],
                                      float (&ac)[7], int lane) {
    float prev = __shfl_up(ac[6], 1, 64);
    float nw[7];
#pragma unroll
    for (int k = 0; k < 7; ++k) {
        float left = k ? ac[k-1] : prev;
        float x = fmaf(S[k], L2E, ac[k]);
        float y = fmaf(V[k], L2E, left);
        if (k == 0) y = (lane == 0) ? NEGF : y;
        float m2 = fmaxf(x, y);
        float d  = fminf(x, y) - m2;
        nw[k] = m2 + log2f(1.0f + exp2f(d));
    }
#pragma unroll
    for (int k = 0; k < 7; ++k) ac[k] = nw[k];
}
__device__ __forceinline__ void cstep_b(const float (&S)[7], const float (&V)[7],
                                        float (&ac)[7], int lane) {
    float nxt = __shfl_down(ac[0], 1, 64);
    float nw[7];
#pragma unroll
    for (int k = 0; k < 7; ++k) {
        int gi = 7*lane + k;
        float bn = (k < 6) ? ac[k+1] : nxt;
        float x = fmaf(S[k], L2E, ac[k]);
        float y = fmaf(V[k], L2E, bn);
        y = (gi < NC-1) ? y : NEGF;
        float m2 = fmaxf(x, y);
        float d  = fminf(x, y) - m2;
        float r  = m2 + log2f(1.0f + exp2f(d));
        nw[k] = (gi < NC) ? r : NEGF;
    }
#pragma unroll
    for (int k = 0; k < 7; ++k) ac[k] = nw[k];
}

// ===================== fast CTC: streaming reads from imgS ==================
__device__ void ctcs_run(const float* __restrict__ imgS, const int* __restrict__ tlens,
                         float* __restrict__ wsf, int b, int lane, bool is_fwd){
    const size_t STP = (size_t)NB * 800;
    const float* p = imgS + (size_t)b * 800;
    int si[7], vi[7];
#pragma unroll
    for (int k = 0; k < 7; ++k){
        int gi = 7*lane + k;
        int s_ = gi;              if (s_ > 399) s_ = 399;
        int v_ = is_fwd ? (400 + gi) : (400 + gi + 1);
        if (v_ > 799) v_ = 799;
        si[k] = s_; vi[k] = v_;
    }
    int tl = tlens[b];
    float ac[7];
#pragma unroll
    for (int k = 0; k < 7; ++k){
        int gi = 7*lane + k;
        ac[k] = is_fwd ? ((gi == 0) ? 0.f : NEGF) : ((gi == tl-5) ? 0.f : NEGF);
    }
    float S[5][7], V[5][7];
#pragma unroll
    for (int j = 0; j < 5; ++j){
        size_t t = is_fwd ? (size_t)j : (size_t)(TT-1-j);
#pragma unroll
        for (int k = 0; k < 7; ++k){ S[j][k] = p[t*STP + si[k]]; V[j][k] = p[t*STP + vi[k]]; }
    }
    for (int t = 0; t < HT; t += 5){
#pragma unroll
        for (int j = 0; j < 5; ++j){
            if (is_fwd) cstep(S[j], V[j], ac, lane);
            else        cstep_b(S[j], V[j], ac, lane);
            int ts = t + 5 + j;
            if (ts < HT){
                size_t tt = is_fwd ? (size_t)ts : (size_t)(TT-1-ts);
#pragma unroll
                for (int k = 0; k < 7; ++k){ S[j][k] = p[tt*STP + si[k]]; V[j][k] = p[tt*STP + vi[k]]; }
            }
        }
    }
#pragma unroll
    for (int k = 0; k < 7; ++k){
        int gi = 7*lane + k;
        if (gi < NC) wsf[(is_fwd ? WS_AC : WS_BC) + b*NC + gi] = ac[k];
    }
}

// ===================== fallback CTC: direct gathers =========================
__device__ __forceinline__ int tgv(const int* targets, int b, int i){
    i = i < 0 ? 0 : (i > LT-1 ? LT-1 : i);
    int v = targets[b*LT + i] - 1;
    return v < 0 ? 0 : v;
}
__device__ void ctcg_run(const float* __restrict__ scores, const int* __restrict__ targets,
                         const int* __restrict__ tlens, float* __restrict__ wsf,
                         int b, int lane, bool is_fwd){
    int so[7], mo[7];
#pragma unroll
    for (int k = 0; k < 7; ++k){
        int gi = 7*lane + k;
        if (gi < NC){
            int K = tgv(targets,b,gi);
            K = K*4 + tgv(targets,b,gi+1); K = K*4 + tgv(targets,b,gi+2);
            K = K*4 + tgv(targets,b,gi+3); K = K*4 + tgv(targets,b,gi+4);
            so[k] = K*5;
            if (is_fwd) mo[k] = (gi >= 1) ? (so[k] + tgv(targets,b,gi-1) + 1) : 0;
            else if (gi < NC-1){
                int K2 = tgv(targets,b,gi+1);
                K2 = K2*4 + tgv(targets,b,gi+2); K2 = K2*4 + tgv(targets,b,gi+3);
                K2 = K2*4 + tgv(targets,b,gi+4); K2 = K2*4 + tgv(targets,b,gi+5);
                mo[k] = K2*5 + tgv(targets,b,gi) + 1;
            } else mo[k] = 0;
        } else { so[k] = 0; mo[k] = 0; }
    }
    int tl = tlens[b];
    float ac[7];
#pragma unroll
    for (int k = 0; k < 7; ++k){
        int gi = 7*lane + k;
        ac[k] = is_fwd ? ((gi == 0) ? 0.f : NEGF) : ((gi == tl-5) ? 0.f : NEGF);
    }
    const size_t STP = (size_t)NB*CD;
    const float* qb = scores + (size_t)b*CD;
    float S[5][7], V[5][7];
#pragma unroll
    for (int j = 0; j < 5; ++j){
        const float* q = qb + (size_t)(is_fwd ? j : (TT-1-j))*STP;
#pragma unroll
        for (int k = 0; k < 7; ++k){ S[j][k] = q[so[k]]; V[j][k] = q[mo[k]]; }
    }
    for (int t = 0; t < HT; t += 5){
#pragma unroll
        for (int j = 0; j < 5; ++j){
            if (is_fwd) cstep(S[j],V[j],ac,lane); else cstep_b(S[j],V[j],ac,lane);
            int ts = t + 5 + j;
            if (ts < HT){
                const float* q = qb + (size_t)(is_fwd ? ts : (TT-1-ts))*STP;
#pragma unroll
                for (int k = 0; k < 7; ++k){ S[j][k] = q[so[k]]; V[j][k] = q[mo[k]]; }
            }
        }
    }
#pragma unroll
    for (int k = 0; k < 7; ++k){
        int gi = 7*lane + k;
        if (gi < NC) wsf[(is_fwd ? WS_AC : WS_BC) + b*NC + gi] = ac[k];
    }
}

// ===================== kernel A: build ctc stream image =====================
extern "C" __global__ void __launch_bounds__(256, 1)
conv_s(const float* __restrict__ scores, float* __restrict__ imgS,
       const int* __restrict__ targets)
{
    const size_t s = blockIdx.x;
    const int tid = threadIdx.x;
    const int b = (int)(s & 31);
    const float* in = scores + s*(size_t)CD;
    float* os = imgS + s*(size_t)800;
    for (int i = tid; i < 800; i += 256){
        float v = 0.f;
        if (i < NC){
            int gi = i;
            int K = tgv(targets,b,gi);
            K = K*4 + tgv(targets,b,gi+1); K = K*4 + tgv(targets,b,gi+2);
            K = K*4 + tgv(targets,b,gi+3); K = K*4 + tgv(targets,b,gi+4);
            v = in[K*5];
        } else if (i >= 401 && i <= 400 + NC - 1){
            int gi = i - 400;
            int K = tgv(targets,b,gi);
            K = K*4 + tgv(targets,b,gi+1); K = K*4 + tgv(targets,b,gi+2);
            K = K*4 + tgv(targets,b,gi+3); K = K*4 + tgv(targets,b,gi+4);
            v = in[K*5 + tgv(targets,b,gi-1) + 1];
        }
        os[i] = v;
    }
}

// ===================== kernel B: trellis + ctc ==============================
extern "C" __global__ void __launch_bounds__(256, 1)
main_k(const float* __restrict__ scores, const float* __restrict__ imgS,
       const int* __restrict__ targets, const int* __restrict__ tlens,
       float* __restrict__ wsf, int useFast)
{
    extern __shared__ float smf[];
    char* sm = (char*)smf;
    const int tid = threadIdx.x, blk = blockIdx.x;
    if (blk < 2*NB){
        trellis_exp(scores, wsf, blk, tid, sm);
        return;
    }
    if (tid >= 64) return;
    const int cb = blk - 2*NB;
    const bool is_fwd = cb < NB;
    const int b = cb & (NB-1);
    if (useFast) ctcs_run(imgS, tlens, wsf, b, tid, is_fwd);
    else         ctcg_run(scores, targets, tlens, wsf, b, tid, is_fwd);
}

// ===================== kernel C: combine ====================================
extern "C" __global__ void __launch_bounds__(256, 1)
ctc_crf_combine(const float* __restrict__ wsf, const int* __restrict__ tlens,
                float* __restrict__ out)
{
    const int b = blockIdx.x, tid = threadIdx.x, lane = tid & 63, w = tid >> 6;
    __shared__ float r1[4], r2[4];
    float4 a4 = *(const float4*)&wsf[WS_AT + b*RS + 4*tid];
    float4 b4 = *(const float4*)&wsf[WS_BT + b*RS + 4*tid];
    float v0 = a4.x+b4.x, v1 = a4.y+b4.y, v2 = a4.z+b4.z, v3 = a4.w+b4.w;
    float m = fmaxf(fmaxf(v0,v1), fmaxf(v2,v3));
#pragma unroll
    for (int o = 32; o >= 1; o >>= 1) m = fmaxf(m, __shfl_xor(m, o, 64));
    if (lane == 0) r1[w] = m;
    __syncthreads();
    float g = fmaxf(fmaxf(r1[0],r1[1]), fmaxf(r1[2],r1[3]));
    float e = exp2f(v0-g)+exp2f(v1-g)+exp2f(v2-g)+exp2f(v3-g);
#pragma unroll
    for (int o = 32; o >= 1; o >>= 1) e += __shfl_xor(e, o, 64);
    if (lane == 0) r2[w] = e;
    __syncthreads();
    float zfull = g + log2f(r2[0]+r2[1]+r2[2]+r2[3]);
    __syncthreads();
    float c0 = (tid < NC)     ? wsf[WS_AC + b*NC + tid]       + wsf[WS_BC + b*NC + tid]       : NEGF;
    float c1 = (tid+256 < NC) ? wsf[WS_AC + b*NC + tid + 256] + wsf[WS_BC + b*NC + tid + 256] : NEGF;
    float mc = fmaxf(c0, c1);
#pragma unroll
    for (int o = 32; o >= 1; o >>= 1) mc = fmaxf(mc, __shfl_xor(mc, o, 64));
    if (lane == 0) r1[w] = mc;
    __syncthreads();
    float gc = fmaxf(fmaxf(r1[0],r1[1]), fmaxf(r1[2],r1[3]));
    float ec = exp2f(c0-gc)+exp2f(c1-gc);
#pragma unroll
    for (int o = 32; o >= 1; o >>= 1) ec += __shfl_xor(ec, o, 64);
    if (lane == 0) r2[w] = ec;
    __syncthreads();
    if (tid == 0){
        float zctc = gc + log2f(r2[0]+r2[1]+r2[2]+r2[3]);
        int tl = tlens[b];
        float loss_b = LN2f * (zfull - zctc) / (float)tl;
        atomicAdd(out, loss_b / (float)NB);
    }
}

extern "C" void kernel_launch(void* const* d_in, const int* in_sizes, int n_in,
                              void* d_out, int out_size, void* d_ws, size_t ws_size,
                              hipStream_t stream) {
    const float* scores  = (const float*)d_in[0];
    const int*   targets = (const int*)d_in[1];
    const int*   tlens   = (const int*)d_in[2];
    float* out = (float*)d_out;

    const size_t need = IMGS_BYTES + (size_t)WSF_FLOATS*4 + 1024;
    const int useFast = (ws_size >= need) ? 1 : 0;
    float* imgS = (float*)d_ws;
    float* wsf  = useFast ? (float*)((char*)d_ws + IMGS_BYTES) : (float*)d_ws;

    hipFuncSetAttribute((const void*)main_k,
                        hipFuncAttributeMaxDynamicSharedMemorySize, SMEM_TR);
    hipMemsetAsync(out, 0, sizeof(float), stream);
    if (useFast)
        conv_s<<<TT*NB, 256, 0, stream>>>(scores, imgS, targets);
    main_k<<<4*NB, 256, SMEM_TR, stream>>>(scores, imgS, targets, tlens, wsf, useFast);
    ctc_crf_combine<<<NB, 256, 0, stream>>>(wsf, tlens, out);
}